// Round 10
// baseline (265.257 us; speedup 1.0000x reference)
//
#include <hip/hip_runtime.h>
#include <stdint.h>

typedef unsigned short ushort_t;
typedef __bf16 bf16x8 __attribute__((ext_vector_type(8)));
typedef float f32x4 __attribute__((ext_vector_type(4)));
typedef unsigned short u16x8 __attribute__((ext_vector_type(8)));

#define TAU_F 0.07f
#define C2F 20.60992915555662f   // log2(e)/tau
#define INV_TAU 14.285714285714286f
#define NBLK 256u

#if __has_builtin(__builtin_amdgcn_exp2f)
#define EXP2F(x) __builtin_amdgcn_exp2f(x)   // single v_exp_f32
#else
#define EXP2F(x) exp2f(x)                    // OCML fallback
#endif

// ---- workspace layout (bytes) ----
#define A_OFF     0u          // bf16 matrix: 8192*128*2 = 2097152
#define LSUM_OFF  2097152u    // lsum partials: 8 slices * 8192 * 4 = 262144
#define SPART_OFF 2359296u    // transposed class-sum partials: 1280*256*4 = 1310720
#define CPART_OFF 3670016u    // transposed count partials: 16*256*4 = 16384
#define S_OFF     3686400u    // reduced class sums: 1280*4
#define CNT_OFF   3691520u    // reduced counts: 16*4
#define BAR_OFF   3691584u    // barrier state: 3 slots * 256B = 768, pad 1024
#define ACC_OFF   3692608u    // loss accum: 2*4
#define ZERO_LEN  1088u       // BAR_OFF..ACC_OFF+64 (only bar+acc need zeroing)

__device__ __forceinline__ ushort_t f2bf(float x) {
  uint32_t u = __float_as_uint(x);
  u += 0x7FFFu + ((u >> 16) & 1u);   // round-to-nearest-even
  return (ushort_t)(u >> 16);
}

__device__ __forceinline__ void gll16(const void* g, void* l) {
  __builtin_amdgcn_global_load_lds(
      (const __attribute__((address_space(1))) uint32_t*)g,
      (__attribute__((address_space(3))) uint32_t*)l, 16, 0, 0);
}

// Contention-safe grid barrier (sense-flag). Arrivals atomicAdd a counter;
// the LAST arriver stores a release flag on a DIFFERENT cacheline; waiters
// read-only poll the flag with s_sleep(16) backoff. Requires co-residency:
// 128KB LDS -> 1 block/CU, grid=256=CUs (empirically validated in R9).
__device__ __forceinline__ void gridbar(uint32_t* bar, int slot) {
  uint32_t* ctr = bar + slot * 64;        // 256B-strided slot
  uint32_t* rel = ctr + 32;               // +128B: separate line from ctr
  __threadfence();                        // release all prior writes
  __syncthreads();
  if (threadIdx.x == 0) {
    uint32_t old = __hip_atomic_fetch_add(ctr, 1u, __ATOMIC_ACQ_REL,
                                          __HIP_MEMORY_SCOPE_AGENT);
    if (old == NBLK - 1u) {
      __hip_atomic_store(rel, 1u, __ATOMIC_RELEASE, __HIP_MEMORY_SCOPE_AGENT);
    } else {
      while (__hip_atomic_load(rel, __ATOMIC_ACQUIRE,
                               __HIP_MEMORY_SCOPE_AGENT) == 0u)
        __builtin_amdgcn_s_sleep(16);     // ~1024 cyc backoff
    }
  }
  __syncthreads();
  __threadfence();                        // acquire side
}

// ---------------------------------------------------------------------------
// ONE fused persistent kernel. 256 blocks x 512 threads, 128 KB LDS.
// P1 prep (partials, no global atomics) -> bar0 -> S-reduce + P2 gemm+exp-sum
// -> bar1 -> P3 row-finalize + publish.
// ---------------------------------------------------------------------------
__global__ __launch_bounds__(512, 2) void k_fused(const float* __restrict__ emb,
                                                  const int* __restrict__ labels,
                                                  ushort_t* __restrict__ abf,
                                                  float* __restrict__ lsum_out,
                                                  float* __restrict__ spart_t,
                                                  int* __restrict__ cpart_t,
                                                  float* __restrict__ S,
                                                  int* __restrict__ cnt,
                                                  uint32_t* __restrict__ bar,
                                                  float* __restrict__ acc,
                                                  float* __restrict__ out) {
  __shared__ __attribute__((aligned(16))) char lds[131072];
  const int tid = threadIdx.x;
  const int b = blockIdx.x;

  // ===================== P1: convert + per-block class partials ============
  {
    float* ssh = (float*)lds;            // 1280 f32
    int* csh = (int*)(lds + 5120);       // 16 i32
    for (int i = tid; i < 1280; i += 512) ssh[i] = 0.f;
    if (tid < 16) csh[tid] = 0;
    __syncthreads();

    const int r = b * 32 + (tid >> 4);       // 32 rows/block
    const int c0 = (tid & 15) * 8;           // 8 floats/thread
    const int lab = labels[r];
    float4 f0 = *(const float4*)(emb + (size_t)r * 128 + c0);
    float4 f1 = *(const float4*)(emb + (size_t)r * 128 + c0 + 4);
    u16x8 o;
    o[0] = f2bf(f0.x); o[1] = f2bf(f0.y); o[2] = f2bf(f0.z); o[3] = f2bf(f0.w);
    o[4] = f2bf(f1.x); o[5] = f2bf(f1.y); o[6] = f2bf(f1.z); o[7] = f2bf(f1.w);
    *(u16x8*)(abf + (size_t)r * 128 + c0) = o;

    atomicAdd(&ssh[lab * 128 + c0 + 0], f0.x);
    atomicAdd(&ssh[lab * 128 + c0 + 1], f0.y);
    atomicAdd(&ssh[lab * 128 + c0 + 2], f0.z);
    atomicAdd(&ssh[lab * 128 + c0 + 3], f0.w);
    atomicAdd(&ssh[lab * 128 + c0 + 4], f1.x);
    atomicAdd(&ssh[lab * 128 + c0 + 5], f1.y);
    atomicAdd(&ssh[lab * 128 + c0 + 6], f1.z);
    atomicAdd(&ssh[lab * 128 + c0 + 7], f1.w);
    if (c0 == 0) atomicAdd(&csh[lab], 1);
    __syncthreads();

    // transposed partial stores (no global atomics; L2-resident scatter)
    for (int i = tid; i < 1280; i += 512) spart_t[(size_t)i * 256 + b] = ssh[i];
    if (tid < 16) cpart_t[tid * 256 + b] = csh[tid];
  }
  gridbar(bar, 0);   // abf + spart_t + cpart_t complete

  // ===================== P1.5: distributed S/cnt reduce ====================
  // block b owns elements [b*5, b*5+5); coalesced float4 loads + shfl tree.
  {
    const int lane = tid & 63;
    const int wave = tid >> 6;
    if (wave < 5) {
      const int i = b * 5 + wave;          // 0..1279
      float4 v = *(const float4*)(spart_t + (size_t)i * 256 + lane * 4);
      float s = v.x + v.y + v.z + v.w;
#pragma unroll
      for (int m = 1; m < 64; m <<= 1) s += __shfl_xor(s, m);
      if (lane == 0) S[i] = s;
    } else if (wave == 5 && b < 16) {
      int4 v = *(const int4*)(cpart_t + b * 256 + lane * 4);
      int s = v.x + v.y + v.z + v.w;
#pragma unroll
      for (int m = 1; m < 64; m <<= 1) s += __shfl_xor(s, m);
      if (lane == 0) cnt[b] = s;
    }
  }

  // ===================== P2: gemm_bt + fixed-max exp-sum (frozen) ==========
  {
    const int lane = tid & 63;
    const int wave = tid >> 6;
    const int lo = lane & 15, hi = lane >> 4;
    const int wr = wave >> 1, wc = wave & 1;
    const int band = b & 31;
    const int slice = b >> 5;
    const int row0 = band * 256;
    const int col0 = slice * 1024;

#pragma unroll
    for (int i = 0; i < 8; ++i) {
      int p = i * 512 + tid;
      int r = p >> 4, s = p & 15;
      const ushort_t* g = abf + (size_t)(row0 + r) * 128 + ((s ^ (r & 7)) << 3);
      gll16(g, lds + (size_t)(i * 512 + wave * 64) * 16);
    }
#pragma unroll
    for (int i = 0; i < 4; ++i) {
      int p = i * 512 + tid;
      int r = p >> 4, s = p & 15;
      const ushort_t* g = abf + (size_t)(col0 + r) * 128 + ((s ^ (r & 7)) << 3);
      gll16(g, lds + 65536 + (size_t)(i * 512 + wave * 64) * 16);
    }
    asm volatile("s_waitcnt vmcnt(0)" ::: "memory");
    __builtin_amdgcn_s_barrier();
    __builtin_amdgcn_sched_barrier(0);

    bf16x8 af[4][4];
#pragma unroll
    for (int mf = 0; mf < 4; ++mf) {
#pragma unroll
      for (int ks = 0; ks < 4; ++ks) {
        int r = wr * 64 + mf * 16 + lo;
        int kb = ks * 64 + hi * 16;
        af[mf][ks] = *(const bf16x8*)(lds + r * 256 + (kb ^ ((r & 7) << 4)));
      }
    }

    float lsum[4][4];
#pragma unroll
    for (int mf = 0; mf < 4; ++mf)
#pragma unroll
      for (int q = 0; q < 4; ++q) lsum[mf][q] = 0.f;

    int cur = 0;
    for (int t = 0; t < 8; ++t) {
      if (t < 7) {
        const int tc0 = col0 + (t + 1) * 128;
        char* buf = lds + 65536 + (cur ^ 1) * 32768;
#pragma unroll
        for (int i = 0; i < 4; ++i) {
          int p = i * 512 + tid;
          int r = p >> 4, s = p & 15;
          const ushort_t* g = abf + (size_t)(tc0 + r) * 128 + ((s ^ (r & 7)) << 3);
          gll16(g, buf + (size_t)(i * 512 + wave * 64) * 16);
        }
      }
      const char* bb = lds + 65536 + cur * 32768;
      f32x4 acc2[4][4];
      const f32x4 z = {0.f, 0.f, 0.f, 0.f};
#pragma unroll
      for (int mf = 0; mf < 4; ++mf)
#pragma unroll
        for (int nf = 0; nf < 4; ++nf) acc2[mf][nf] = z;

#pragma unroll
      for (int ks = 0; ks < 4; ++ks) {
        bf16x8 bfr[4];
#pragma unroll
        for (int nf = 0; nf < 4; ++nf) {
          int c = wc * 64 + nf * 16 + lo;
          int kb = ks * 64 + hi * 16;
          bfr[nf] = *(const bf16x8*)(bb + c * 256 + (kb ^ ((c & 7) << 4)));
        }
#pragma unroll
        for (int mf = 0; mf < 4; ++mf)
#pragma unroll
          for (int nf = 0; nf < 4; ++nf)
            acc2[mf][nf] = __builtin_amdgcn_mfma_f32_16x16x32_bf16(
                af[mf][ks], bfr[nf], acc2[mf][nf], 0, 0, 0);
      }

      const int gr0 = row0 + wr * 64;
      const int gc0 = col0 + t * 128 + wc * 64;
      const bool diag = (gr0 == gc0);
#pragma unroll
      for (int mf = 0; mf < 4; ++mf) {
#pragma unroll
        for (int nf = 0; nf < 4; ++nf) {
#pragma unroll
          for (int q = 0; q < 4; ++q) {
            float d = acc2[mf][nf][q];
            float e = EXP2F(fmaf(d, C2F, -C2F));
            if (diag && (mf * 16 + hi * 4 + q) == (nf * 16 + lo)) e = 0.f;
            lsum[mf][q] += e;
          }
        }
      }

      asm volatile("s_waitcnt vmcnt(0)" ::: "memory");
      __builtin_amdgcn_s_barrier();
      __builtin_amdgcn_sched_barrier(0);
      cur ^= 1;
    }

#pragma unroll
    for (int mf = 0; mf < 4; ++mf) {
#pragma unroll
      for (int q = 0; q < 4; ++q) {
        float v = lsum[mf][q];
        v += __shfl_xor(v, 1);
        v += __shfl_xor(v, 2);
        v += __shfl_xor(v, 4);
        v += __shfl_xor(v, 8);
        lsum[mf][q] = v;
      }
    }
    float* lsh = (float*)lds;
    __syncthreads();
    if (lo == 0 && wc == 0) {
#pragma unroll
      for (int mf = 0; mf < 4; ++mf)
#pragma unroll
        for (int q = 0; q < 4; ++q)
          lsh[wr * 64 + mf * 16 + hi * 4 + q] = lsum[mf][q];
    }
    __syncthreads();
    if (lo == 0 && wc == 1) {
#pragma unroll
      for (int mf = 0; mf < 4; ++mf)
#pragma unroll
        for (int q = 0; q < 4; ++q)
          lsh[wr * 64 + mf * 16 + hi * 4 + q] += lsum[mf][q];
    }
    __syncthreads();
    if (tid < 256) lsum_out[(size_t)slice * 8192 + row0 + tid] = lsh[tid];
  }
  gridbar(bar, 1);   // lsum + S + cnt complete

  // ===================== P3: per-row finalize + publish ====================
  {
    const int lane = tid & 63;
    const int w = tid >> 6;          // 0..7
    float lossacc = 0.f, ancacc = 0.f;
#pragma unroll
    for (int rr = 0; rr < 4; ++rr) {
      const int i = b * 32 + w * 4 + rr;
      const int lab = labels[i];
      float2 a = ((const float2*)(emb + (size_t)i * 128))[lane];
      float2 s = ((const float2*)(S + (size_t)lab * 128))[lane];
      float pd = a.x * s.x + a.y * s.y;
      float sd = a.x * a.x + a.y * a.y;
#pragma unroll
      for (int m = 1; m < 64; m <<= 1) { pd += __shfl_xor(pd, m); sd += __shfl_xor(sd, m); }
      float ls = (lane < 8) ? lsum_out[(size_t)lane * 8192 + i] : 0.f;
      ls += __shfl_xor(ls, 1); ls += __shfl_xor(ls, 2); ls += __shfl_xor(ls, 4);
      if (lane == 0) {
        int np = cnt[lab] - 1;
        if (np > 0) {
          float logden = logf(ls) + INV_TAU;   // fixed-max LSE: sim bound = 1/tau
          lossacc += logden - (pd - sd) / (TAU_F * (float)np);
          ancacc += 1.f;
        }
      }
    }
    float* red = (float*)lds;
    if (lane == 0) { red[w * 2] = lossacc; red[w * 2 + 1] = ancacc; }
    __syncthreads();
    if (tid == 0) {
      float sl = 0.f, sa = 0.f;
#pragma unroll
      for (int k = 0; k < 8; ++k) { sl += red[k * 2]; sa += red[k * 2 + 1]; }
      atomicAdd(&acc[0], sl);
      atomicAdd(&acc[1], sa);
      __threadfence();
      uint32_t old = atomicAdd(bar + 2 * 64, 1u);   // arrival count (slot 2)
      if (old == NBLK - 1u) {
        __threadfence();   // acquire: order acc reads after all arrivals
        float L = __hip_atomic_load(&acc[0], __ATOMIC_RELAXED, __HIP_MEMORY_SCOPE_AGENT);
        float A = __hip_atomic_load(&acc[1], __ATOMIC_RELAXED, __HIP_MEMORY_SCOPE_AGENT);
        out[0] = L / fmaxf(A, 1.0f);
      }
    }
  }
}

// ---------------------------------------------------------------------------
extern "C" void kernel_launch(void* const* d_in, const int* in_sizes, int n_in,
                              void* d_out, int out_size, void* d_ws, size_t ws_size,
                              hipStream_t stream) {
  const float* emb = (const float*)d_in[0];
  const int* labels = (const int*)d_in[1];
  char* ws = (char*)d_ws;
  ushort_t* abf   = (ushort_t*)(ws + A_OFF);
  float* lsum     = (float*)(ws + LSUM_OFF);
  float* spart_t  = (float*)(ws + SPART_OFF);
  int*   cpart_t  = (int*)(ws + CPART_OFF);
  float* S        = (float*)(ws + S_OFF);
  int*   cnt      = (int*)(ws + CNT_OFF);
  uint32_t* bar   = (uint32_t*)(ws + BAR_OFF);
  float* acc      = (float*)(ws + ACC_OFF);
  float* out      = (float*)d_out;

  // zero barrier state + loss accumulators (re-runs every replay)
  hipMemsetAsync(ws + BAR_OFF, 0, ZERO_LEN, stream);
  hipLaunchKernelGGL(k_fused, dim3(NBLK), dim3(512), 0, stream,
                     emb, labels, abf, lsum, spart_t, cpart_t, S, cnt, bar, acc, out);
}

// Round 13
// 174.622 us; speedup vs baseline: 1.5190x; 1.5190x over previous
//
#include <hip/hip_runtime.h>
#include <stdint.h>

typedef unsigned short ushort_t;
typedef __bf16 bf16x8 __attribute__((ext_vector_type(8)));
typedef float f32x4 __attribute__((ext_vector_type(4)));
typedef unsigned short u16x8 __attribute__((ext_vector_type(8)));

#define TAU_F 0.07f
#define C2F 20.60992915555662f   // log2(e)/tau
#define INV_TAU 14.285714285714286f

#if __has_builtin(__builtin_amdgcn_exp2f)
#define EXP2F(x) __builtin_amdgcn_exp2f(x)   // single v_exp_f32
#else
#define EXP2F(x) exp2f(x)                    // OCML fallback
#endif

// ---- workspace layout (bytes) ----
#define A_OFF     0u          // bf16 matrix: 8192*128*2 = 2097152
#define LSUM_OFF  2097152u    // lsum partials: 8 slices * 8192 * 4 = 262144
#define S8_OFF    2359296u    // radix-8 class-sum copies: 8*1280*4 = 40960
#define CNT8_OFF  2400256u    // radix-8 count copies: 8*16*4 = 512
#define S_OFF     2400768u    // reduced class sums: 1280*4 = 5120
#define CNT_OFF   2405888u    // reduced counts: 16*4 (pad 64)
#define BAR_OFF   2405952u    // k_row arrival counter (pad 64)
#define ACC_OFF   2406016u    // loss accum: 2*4 (pad 64)
#define ZERO_LEN  46784u      // S8_OFF .. ACC_OFF+64

__device__ __forceinline__ ushort_t f2bf(float x) {
  uint32_t u = __float_as_uint(x);
  u += 0x7FFFu + ((u >> 16) & 1u);   // round-to-nearest-even
  return (ushort_t)(u >> 16);
}

__device__ __forceinline__ void gll16(const void* g, void* l) {
  __builtin_amdgcn_global_load_lds(
      (const __attribute__((address_space(1))) uint32_t*)g,
      (__attribute__((address_space(3))) uint32_t*)l, 16, 0, 0);
}

// ---------------------------------------------------------------------------
// Kernel 1: fp32 -> bf16 convert + class sums into RADIX-8 shadow copies
// (block b -> copy b&7): per-address atomic chain 256 -> 32.
// grid 256 x 512 ; block b handles rows [b*32, b*32+32)
// ---------------------------------------------------------------------------
__global__ __launch_bounds__(512) void k_prep(const float* __restrict__ emb,
                                              const int* __restrict__ labels,
                                              ushort_t* __restrict__ abf,
                                              float* __restrict__ S8,
                                              int* __restrict__ cnt8) {
  __shared__ float ssh[1280];
  __shared__ int csh[16];
  const int tid = threadIdx.x, b = blockIdx.x;
  for (int i = tid; i < 1280; i += 512) ssh[i] = 0.f;
  if (tid < 16) csh[tid] = 0;
  __syncthreads();

  const int r = b * 32 + (tid >> 4);       // 32 rows/block
  const int c0 = (tid & 15) * 8;           // 8 floats/thread
  const int lab = labels[r];
  float4 f0 = *(const float4*)(emb + (size_t)r * 128 + c0);
  float4 f1 = *(const float4*)(emb + (size_t)r * 128 + c0 + 4);
  u16x8 o;
  o[0] = f2bf(f0.x); o[1] = f2bf(f0.y); o[2] = f2bf(f0.z); o[3] = f2bf(f0.w);
  o[4] = f2bf(f1.x); o[5] = f2bf(f1.y); o[6] = f2bf(f1.z); o[7] = f2bf(f1.w);
  *(u16x8*)(abf + (size_t)r * 128 + c0) = o;

  atomicAdd(&ssh[lab * 128 + c0 + 0], f0.x);
  atomicAdd(&ssh[lab * 128 + c0 + 1], f0.y);
  atomicAdd(&ssh[lab * 128 + c0 + 2], f0.z);
  atomicAdd(&ssh[lab * 128 + c0 + 3], f0.w);
  atomicAdd(&ssh[lab * 128 + c0 + 4], f1.x);
  atomicAdd(&ssh[lab * 128 + c0 + 5], f1.y);
  atomicAdd(&ssh[lab * 128 + c0 + 6], f1.z);
  atomicAdd(&ssh[lab * 128 + c0 + 7], f1.w);
  if (c0 == 0) atomicAdd(&csh[lab], 1);
  __syncthreads();

  float* Sc = S8 + (size_t)(b & 7) * 1280;
  for (int i = tid; i < 1280; i += 512) atomicAdd(&Sc[i], ssh[i]);
  if (tid < 16 && csh[tid] != 0) atomicAdd(&cnt8[(b & 7) * 16 + tid], csh[tid]);
}

// ---------------------------------------------------------------------------
// Kernel 2: reduce the 8 shadow copies. grid 3 x 512 (1536 >= 1280 threads)
// ---------------------------------------------------------------------------
__global__ __launch_bounds__(512) void k_reduce(const float* __restrict__ S8,
                                                const int* __restrict__ cnt8,
                                                float* __restrict__ S,
                                                int* __restrict__ cnt) {
  const int i = blockIdx.x * 512 + threadIdx.x;
  if (i < 1280) {
    float s = 0.f;
#pragma unroll
    for (int c = 0; c < 8; ++c) s += S8[c * 1280 + i];
    S[i] = s;
  }
  if (i < 16) {
    int s = 0;
#pragma unroll
    for (int c = 0; c < 8; ++c) s += cnt8[c * 16 + i];
    cnt[i] = s;
  }
}

// ---------------------------------------------------------------------------
// Kernel 3 (main, FROZEN = R4): bf16 MFMA gemm_bt fused with fixed-max exp-sum.
// grid 256 x 512. Block = 256 rows x 1024 cols, K=128 in regs.
// ---------------------------------------------------------------------------
__global__ __launch_bounds__(512, 2) void k_main(const ushort_t* __restrict__ abf,
                                                 float* __restrict__ lsum_out) {
  __shared__ __attribute__((aligned(16))) char lds[131072];
  const int tid = threadIdx.x;
  const int lane = tid & 63;
  const int wave = tid >> 6;       // 0..7
  const int lo = lane & 15, hi = lane >> 4;
  const int wr = wave >> 1, wc = wave & 1;
  const int band = blockIdx.x & 31;
  const int slice = blockIdx.x >> 5;
  const int row0 = band * 256;
  const int col0 = slice * 1024;

#pragma unroll
  for (int i = 0; i < 8; ++i) {
    int p = i * 512 + tid;
    int r = p >> 4, s = p & 15;
    const ushort_t* g = abf + (size_t)(row0 + r) * 128 + ((s ^ (r & 7)) << 3);
    gll16(g, lds + (size_t)(i * 512 + wave * 64) * 16);
  }
#pragma unroll
  for (int i = 0; i < 4; ++i) {
    int p = i * 512 + tid;
    int r = p >> 4, s = p & 15;
    const ushort_t* g = abf + (size_t)(col0 + r) * 128 + ((s ^ (r & 7)) << 3);
    gll16(g, lds + 65536 + (size_t)(i * 512 + wave * 64) * 16);
  }
  asm volatile("s_waitcnt vmcnt(0)" ::: "memory");
  __builtin_amdgcn_s_barrier();
  __builtin_amdgcn_sched_barrier(0);

  bf16x8 af[4][4];
#pragma unroll
  for (int mf = 0; mf < 4; ++mf) {
#pragma unroll
    for (int ks = 0; ks < 4; ++ks) {
      int r = wr * 64 + mf * 16 + lo;
      int kb = ks * 64 + hi * 16;
      af[mf][ks] = *(const bf16x8*)(lds + r * 256 + (kb ^ ((r & 7) << 4)));
    }
  }

  float lsum[4][4];
#pragma unroll
  for (int mf = 0; mf < 4; ++mf)
#pragma unroll
    for (int q = 0; q < 4; ++q) lsum[mf][q] = 0.f;

  int cur = 0;
  for (int t = 0; t < 8; ++t) {
    if (t < 7) {
      const int tc0 = col0 + (t + 1) * 128;
      char* buf = lds + 65536 + (cur ^ 1) * 32768;
#pragma unroll
      for (int i = 0; i < 4; ++i) {
        int p = i * 512 + tid;
        int r = p >> 4, s = p & 15;
        const ushort_t* g = abf + (size_t)(tc0 + r) * 128 + ((s ^ (r & 7)) << 3);
        gll16(g, buf + (size_t)(i * 512 + wave * 64) * 16);
      }
    }
    const char* bb = lds + 65536 + cur * 32768;
    f32x4 acc2[4][4];
    const f32x4 z = {0.f, 0.f, 0.f, 0.f};
#pragma unroll
    for (int mf = 0; mf < 4; ++mf)
#pragma unroll
      for (int nf = 0; nf < 4; ++nf) acc2[mf][nf] = z;

#pragma unroll
    for (int ks = 0; ks < 4; ++ks) {
      bf16x8 bfr[4];
#pragma unroll
      for (int nf = 0; nf < 4; ++nf) {
        int c = wc * 64 + nf * 16 + lo;
        int kb = ks * 64 + hi * 16;
        bfr[nf] = *(const bf16x8*)(bb + c * 256 + (kb ^ ((c & 7) << 4)));
      }
#pragma unroll
      for (int mf = 0; mf < 4; ++mf)
#pragma unroll
        for (int nf = 0; nf < 4; ++nf)
          acc2[mf][nf] = __builtin_amdgcn_mfma_f32_16x16x32_bf16(
              af[mf][ks], bfr[nf], acc2[mf][nf], 0, 0, 0);
    }

    const int gr0 = row0 + wr * 64;
    const int gc0 = col0 + t * 128 + wc * 64;
    const bool diag = (gr0 == gc0);
#pragma unroll
    for (int mf = 0; mf < 4; ++mf) {
#pragma unroll
      for (int nf = 0; nf < 4; ++nf) {
#pragma unroll
        for (int q = 0; q < 4; ++q) {
          float d = acc2[mf][nf][q];
          float e = EXP2F(fmaf(d, C2F, -C2F));
          if (diag && (mf * 16 + hi * 4 + q) == (nf * 16 + lo)) e = 0.f;
          lsum[mf][q] += e;
        }
      }
    }

    asm volatile("s_waitcnt vmcnt(0)" ::: "memory");
    __builtin_amdgcn_s_barrier();
    __builtin_amdgcn_sched_barrier(0);
    cur ^= 1;
  }

#pragma unroll
  for (int mf = 0; mf < 4; ++mf) {
#pragma unroll
    for (int q = 0; q < 4; ++q) {
      float v = lsum[mf][q];
      v += __shfl_xor(v, 1);
      v += __shfl_xor(v, 2);
      v += __shfl_xor(v, 4);
      v += __shfl_xor(v, 8);
      lsum[mf][q] = v;
    }
  }
  float* lsh = (float*)lds;
  __syncthreads();
  if (lo == 0 && wc == 0) {
#pragma unroll
    for (int mf = 0; mf < 4; ++mf)
#pragma unroll
      for (int q = 0; q < 4; ++q)
        lsh[wr * 64 + mf * 16 + hi * 4 + q] = lsum[mf][q];
  }
  __syncthreads();
  if (lo == 0 && wc == 1) {
#pragma unroll
    for (int mf = 0; mf < 4; ++mf)
#pragma unroll
      for (int q = 0; q < 4; ++q)
        lsh[wr * 64 + mf * 16 + hi * 4 + q] += lsum[mf][q];
  }
  __syncthreads();
  if (tid < 256) lsum_out[(size_t)slice * 8192 + row0 + tid] = lsh[tid];
}

// ---------------------------------------------------------------------------
// Kernel 4: per-row finalize + last-block publish (absorbs old k_fin).
// grid 2048 x 256, 4 rows/block.
// ---------------------------------------------------------------------------
__global__ __launch_bounds__(256) void k_row(const float* __restrict__ emb,
                                             const int* __restrict__ labels,
                                             const float* __restrict__ S,
                                             const int* __restrict__ cnt,
                                             const float* __restrict__ lsum_part,
                                             uint32_t* __restrict__ bar,
                                             float* __restrict__ acc,
                                             float* __restrict__ out) {
  const int tid = threadIdx.x;
  const int lane = tid & 63;
  const int w = tid >> 6;                 // 0..3
  const int i = blockIdx.x * 4 + w;       // row
  const int lab = labels[i];
  float2 a = ((const float2*)(emb + (size_t)i * 128))[lane];
  float2 s = ((const float2*)(S + (size_t)lab * 128))[lane];
  float pd = a.x * s.x + a.y * s.y;       // e_i . S_class
  float sd = a.x * a.x + a.y * a.y;       // e_i . e_i
#pragma unroll
  for (int m = 1; m < 64; m <<= 1) { pd += __shfl_xor(pd, m); sd += __shfl_xor(sd, m); }
  float ls = (lane < 8) ? lsum_part[(size_t)lane * 8192 + i] : 0.f;
  ls += __shfl_xor(ls, 1); ls += __shfl_xor(ls, 2); ls += __shfl_xor(ls, 4);

  float loss = 0.f, anc = 0.f;
  if (lane == 0) {
    int np = cnt[lab] - 1;
    if (np > 0) {
      float logden = logf(ls) + INV_TAU;   // fixed-max LSE: sim bound = 1/tau
      loss = logden - (pd - sd) / (TAU_F * (float)np);
      anc = 1.f;
    }
  }
  __shared__ float red[8];
  if (lane == 0) { red[w * 2] = loss; red[w * 2 + 1] = anc; }
  __syncthreads();
  if (tid == 0) {
    atomicAdd(&acc[0], red[0] + red[2] + red[4] + red[6]);
    atomicAdd(&acc[1], red[1] + red[3] + red[5] + red[7]);
    __threadfence();
    uint32_t old = atomicAdd(bar, 1u);     // arrival count
    if (old == 2047u) {                    // last block publishes
      __threadfence();
      float L = __hip_atomic_load(&acc[0], __ATOMIC_RELAXED, __HIP_MEMORY_SCOPE_AGENT);
      float A = __hip_atomic_load(&acc[1], __ATOMIC_RELAXED, __HIP_MEMORY_SCOPE_AGENT);
      out[0] = L / fmaxf(A, 1.0f);
    }
  }
}

// ---------------------------------------------------------------------------
extern "C" void kernel_launch(void* const* d_in, const int* in_sizes, int n_in,
                              void* d_out, int out_size, void* d_ws, size_t ws_size,
                              hipStream_t stream) {
  const float* emb = (const float*)d_in[0];
  const int* labels = (const int*)d_in[1];
  char* ws = (char*)d_ws;
  ushort_t* abf  = (ushort_t*)(ws + A_OFF);
  float* lsum    = (float*)(ws + LSUM_OFF);
  float* S8      = (float*)(ws + S8_OFF);
  int*   cnt8    = (int*)(ws + CNT8_OFF);
  float* S       = (float*)(ws + S_OFF);
  int*   cnt     = (int*)(ws + CNT_OFF);
  uint32_t* bar  = (uint32_t*)(ws + BAR_OFF);
  float* acc     = (float*)(ws + ACC_OFF);
  float* out     = (float*)d_out;

  // zero radix copies + arrival counter + accumulators (every replay)
  hipMemsetAsync(ws + S8_OFF, 0, ZERO_LEN, stream);
  hipLaunchKernelGGL(k_prep,   dim3(256),  dim3(512), 0, stream, emb, labels, abf, S8, cnt8);
  hipLaunchKernelGGL(k_reduce, dim3(3),    dim3(512), 0, stream, S8, cnt8, S, cnt);
  hipLaunchKernelGGL(k_main,   dim3(256),  dim3(512), 0, stream, abf, lsum);
  hipLaunchKernelGGL(k_row,    dim3(2048), dim3(256), 0, stream, emb, labels, S, cnt, lsum, bar, acc, out);
}

// Round 15
// 95.020 us; speedup vs baseline: 2.7916x; 1.8378x over previous
//
#include <hip/hip_runtime.h>
#include <stdint.h>

typedef unsigned short ushort_t;
typedef __bf16 bf16x8 __attribute__((ext_vector_type(8)));
typedef float f32x4 __attribute__((ext_vector_type(4)));
typedef unsigned short u16x8 __attribute__((ext_vector_type(8)));

#define TAU_F 0.07f
#define C2F 20.60992915555662f   // log2(e)/tau
#define INV_TAU 14.285714285714286f

#if __has_builtin(__builtin_amdgcn_exp2f)
#define EXP2F(x) __builtin_amdgcn_exp2f(x)   // single v_exp_f32
#else
#define EXP2F(x) exp2f(x)                    // OCML fallback
#endif

// ---- workspace layout (bytes) ----
#define A_OFF     0u          // bf16 matrix: 8192*128*2 = 2097152
#define LSUM_OFF  2097152u    // lsum partials: 8 slices * 8192 * 4 = 262144
#define S8_OFF    2359296u    // radix-8 class-sum copies: 8*1280*4 = 40960
#define CNT8_OFF  2400256u    // radix-8 count copies: 8*16*4 = 512
#define S_OFF     2400768u    // reduced class sums: 1280*4 = 5120
#define CNT_OFF   2405888u    // reduced counts: 16*4 (pad 64)
#define CBLK_OFF  2405952u    // per-block (loss,anchors): 2048*2*4 = 16384
#define ZERO_LEN  41472u      // S8_OFF .. CNT8 end (radix copies only)

__device__ __forceinline__ ushort_t f2bf(float x) {
  uint32_t u = __float_as_uint(x);
  u += 0x7FFFu + ((u >> 16) & 1u);   // round-to-nearest-even
  return (ushort_t)(u >> 16);
}

__device__ __forceinline__ void gll16(const void* g, void* l) {
  __builtin_amdgcn_global_load_lds(
      (const __attribute__((address_space(1))) uint32_t*)g,
      (__attribute__((address_space(3))) uint32_t*)l, 16, 0, 0);
}

// ---------------------------------------------------------------------------
// Kernel 1: fp32 -> bf16 convert + class sums into RADIX-8 shadow copies
// (block b -> copy b&7): per-address atomic chain 256 -> 32.
// grid 256 x 512 ; block b handles rows [b*32, b*32+32)
// ---------------------------------------------------------------------------
__global__ __launch_bounds__(512) void k_prep(const float* __restrict__ emb,
                                              const int* __restrict__ labels,
                                              ushort_t* __restrict__ abf,
                                              float* __restrict__ S8,
                                              int* __restrict__ cnt8) {
  __shared__ float ssh[1280];
  __shared__ int csh[16];
  const int tid = threadIdx.x, b = blockIdx.x;
  for (int i = tid; i < 1280; i += 512) ssh[i] = 0.f;
  if (tid < 16) csh[tid] = 0;
  __syncthreads();

  const int r = b * 32 + (tid >> 4);       // 32 rows/block
  const int c0 = (tid & 15) * 8;           // 8 floats/thread
  const int lab = labels[r];
  float4 f0 = *(const float4*)(emb + (size_t)r * 128 + c0);
  float4 f1 = *(const float4*)(emb + (size_t)r * 128 + c0 + 4);
  u16x8 o;
  o[0] = f2bf(f0.x); o[1] = f2bf(f0.y); o[2] = f2bf(f0.z); o[3] = f2bf(f0.w);
  o[4] = f2bf(f1.x); o[5] = f2bf(f1.y); o[6] = f2bf(f1.z); o[7] = f2bf(f1.w);
  *(u16x8*)(abf + (size_t)r * 128 + c0) = o;

  atomicAdd(&ssh[lab * 128 + c0 + 0], f0.x);
  atomicAdd(&ssh[lab * 128 + c0 + 1], f0.y);
  atomicAdd(&ssh[lab * 128 + c0 + 2], f0.z);
  atomicAdd(&ssh[lab * 128 + c0 + 3], f0.w);
  atomicAdd(&ssh[lab * 128 + c0 + 4], f1.x);
  atomicAdd(&ssh[lab * 128 + c0 + 5], f1.y);
  atomicAdd(&ssh[lab * 128 + c0 + 6], f1.z);
  atomicAdd(&ssh[lab * 128 + c0 + 7], f1.w);
  if (c0 == 0) atomicAdd(&csh[lab], 1);
  __syncthreads();

  float* Sc = S8 + (size_t)(b & 7) * 1280;
  for (int i = tid; i < 1280; i += 512) atomicAdd(&Sc[i], ssh[i]);
  if (tid < 16 && csh[tid] != 0) atomicAdd(&cnt8[(b & 7) * 16 + tid], csh[tid]);
}

// ---------------------------------------------------------------------------
// Kernel 2: reduce the 8 shadow copies. grid 3 x 512 (1536 >= 1280 threads)
// ---------------------------------------------------------------------------
__global__ __launch_bounds__(512) void k_reduce(const float* __restrict__ S8,
                                                const int* __restrict__ cnt8,
                                                float* __restrict__ S,
                                                int* __restrict__ cnt) {
  const int i = blockIdx.x * 512 + threadIdx.x;
  if (i < 1280) {
    float s = 0.f;
#pragma unroll
    for (int c = 0; c < 8; ++c) s += S8[c * 1280 + i];
    S[i] = s;
  }
  if (i < 16) {
    int s = 0;
#pragma unroll
    for (int c = 0; c < 8; ++c) s += cnt8[c * 16 + i];
    cnt[i] = s;
  }
}

// ---------------------------------------------------------------------------
// Kernel 3 (main, FROZEN = R4): bf16 MFMA gemm_bt fused with fixed-max exp-sum.
// grid 256 x 512. Block = 256 rows x 1024 cols, K=128 in regs.
// ---------------------------------------------------------------------------
__global__ __launch_bounds__(512, 2) void k_main(const ushort_t* __restrict__ abf,
                                                 float* __restrict__ lsum_out) {
  __shared__ __attribute__((aligned(16))) char lds[131072];
  const int tid = threadIdx.x;
  const int lane = tid & 63;
  const int wave = tid >> 6;       // 0..7
  const int lo = lane & 15, hi = lane >> 4;
  const int wr = wave >> 1, wc = wave & 1;
  const int band = blockIdx.x & 31;
  const int slice = blockIdx.x >> 5;
  const int row0 = band * 256;
  const int col0 = slice * 1024;

#pragma unroll
  for (int i = 0; i < 8; ++i) {
    int p = i * 512 + tid;
    int r = p >> 4, s = p & 15;
    const ushort_t* g = abf + (size_t)(row0 + r) * 128 + ((s ^ (r & 7)) << 3);
    gll16(g, lds + (size_t)(i * 512 + wave * 64) * 16);
  }
#pragma unroll
  for (int i = 0; i < 4; ++i) {
    int p = i * 512 + tid;
    int r = p >> 4, s = p & 15;
    const ushort_t* g = abf + (size_t)(col0 + r) * 128 + ((s ^ (r & 7)) << 3);
    gll16(g, lds + 65536 + (size_t)(i * 512 + wave * 64) * 16);
  }
  asm volatile("s_waitcnt vmcnt(0)" ::: "memory");
  __builtin_amdgcn_s_barrier();
  __builtin_amdgcn_sched_barrier(0);

  bf16x8 af[4][4];
#pragma unroll
  for (int mf = 0; mf < 4; ++mf) {
#pragma unroll
    for (int ks = 0; ks < 4; ++ks) {
      int r = wr * 64 + mf * 16 + lo;
      int kb = ks * 64 + hi * 16;
      af[mf][ks] = *(const bf16x8*)(lds + r * 256 + (kb ^ ((r & 7) << 4)));
    }
  }

  float lsum[4][4];
#pragma unroll
  for (int mf = 0; mf < 4; ++mf)
#pragma unroll
    for (int q = 0; q < 4; ++q) lsum[mf][q] = 0.f;

  int cur = 0;
  for (int t = 0; t < 8; ++t) {
    if (t < 7) {
      const int tc0 = col0 + (t + 1) * 128;
      char* buf = lds + 65536 + (cur ^ 1) * 32768;
#pragma unroll
      for (int i = 0; i < 4; ++i) {
        int p = i * 512 + tid;
        int r = p >> 4, s = p & 15;
        const ushort_t* g = abf + (size_t)(tc0 + r) * 128 + ((s ^ (r & 7)) << 3);
        gll16(g, buf + (size_t)(i * 512 + wave * 64) * 16);
      }
    }
    const char* bb = lds + 65536 + cur * 32768;
    f32x4 acc2[4][4];
    const f32x4 z = {0.f, 0.f, 0.f, 0.f};
#pragma unroll
    for (int mf = 0; mf < 4; ++mf)
#pragma unroll
      for (int nf = 0; nf < 4; ++nf) acc2[mf][nf] = z;

#pragma unroll
    for (int ks = 0; ks < 4; ++ks) {
      bf16x8 bfr[4];
#pragma unroll
      for (int nf = 0; nf < 4; ++nf) {
        int c = wc * 64 + nf * 16 + lo;
        int kb = ks * 64 + hi * 16;
        bfr[nf] = *(const bf16x8*)(bb + c * 256 + (kb ^ ((c & 7) << 4)));
      }
#pragma unroll
      for (int mf = 0; mf < 4; ++mf)
#pragma unroll
        for (int nf = 0; nf < 4; ++nf)
          acc2[mf][nf] = __builtin_amdgcn_mfma_f32_16x16x32_bf16(
              af[mf][ks], bfr[nf], acc2[mf][nf], 0, 0, 0);
    }

    const int gr0 = row0 + wr * 64;
    const int gc0 = col0 + t * 128 + wc * 64;
    const bool diag = (gr0 == gc0);
#pragma unroll
    for (int mf = 0; mf < 4; ++mf) {
#pragma unroll
      for (int nf = 0; nf < 4; ++nf) {
#pragma unroll
        for (int q = 0; q < 4; ++q) {
          float d = acc2[mf][nf][q];
          float e = EXP2F(fmaf(d, C2F, -C2F));
          if (diag && (mf * 16 + hi * 4 + q) == (nf * 16 + lo)) e = 0.f;
          lsum[mf][q] += e;
        }
      }
    }

    asm volatile("s_waitcnt vmcnt(0)" ::: "memory");
    __builtin_amdgcn_s_barrier();
    __builtin_amdgcn_sched_barrier(0);
    cur ^= 1;
  }

#pragma unroll
  for (int mf = 0; mf < 4; ++mf) {
#pragma unroll
    for (int q = 0; q < 4; ++q) {
      float v = lsum[mf][q];
      v += __shfl_xor(v, 1);
      v += __shfl_xor(v, 2);
      v += __shfl_xor(v, 4);
      v += __shfl_xor(v, 8);
      lsum[mf][q] = v;
    }
  }
  float* lsh = (float*)lds;
  __syncthreads();
  if (lo == 0 && wc == 0) {
#pragma unroll
    for (int mf = 0; mf < 4; ++mf)
#pragma unroll
      for (int q = 0; q < 4; ++q)
        lsh[wr * 64 + mf * 16 + hi * 4 + q] = lsum[mf][q];
  }
  __syncthreads();
  if (lo == 0 && wc == 1) {
#pragma unroll
    for (int mf = 0; mf < 4; ++mf)
#pragma unroll
      for (int q = 0; q < 4; ++q)
        lsh[wr * 64 + mf * 16 + hi * 4 + q] += lsum[mf][q];
  }
  __syncthreads();
  if (tid < 256) lsum_out[(size_t)slice * 8192 + row0 + tid] = lsh[tid];
}

// ---------------------------------------------------------------------------
// Kernel 4: per-row finalize -> per-block partial stores (NO atomics; the
// R13 lesson: 2048-deep same-address atomic chain cost 93 us).
// grid 2048 x 256, 4 rows/block.
// ---------------------------------------------------------------------------
__global__ __launch_bounds__(256) void k_row(const float* __restrict__ emb,
                                             const int* __restrict__ labels,
                                             const float* __restrict__ S,
                                             const int* __restrict__ cnt,
                                             const float* __restrict__ lsum_part,
                                             float* __restrict__ cblk) {
  const int tid = threadIdx.x;
  const int lane = tid & 63;
  const int w = tid >> 6;                 // 0..3
  const int i = blockIdx.x * 4 + w;       // row
  const int lab = labels[i];
  float2 a = ((const float2*)(emb + (size_t)i * 128))[lane];
  float2 s = ((const float2*)(S + (size_t)lab * 128))[lane];
  float pd = a.x * s.x + a.y * s.y;       // e_i . S_class
  float sd = a.x * a.x + a.y * a.y;       // e_i . e_i
#pragma unroll
  for (int m = 1; m < 64; m <<= 1) { pd += __shfl_xor(pd, m); sd += __shfl_xor(sd, m); }
  float ls = (lane < 8) ? lsum_part[(size_t)lane * 8192 + i] : 0.f;
  ls += __shfl_xor(ls, 1); ls += __shfl_xor(ls, 2); ls += __shfl_xor(ls, 4);

  float loss = 0.f, anc = 0.f;
  if (lane == 0) {
    int np = cnt[lab] - 1;
    if (np > 0) {
      float logden = logf(ls) + INV_TAU;   // fixed-max LSE: sim bound = 1/tau
      loss = logden - (pd - sd) / (TAU_F * (float)np);
      anc = 1.f;
    }
  }
  __shared__ float red[8];
  if (lane == 0) { red[w * 2] = loss; red[w * 2 + 1] = anc; }
  __syncthreads();
  if (tid == 0) {
    cblk[(size_t)blockIdx.x * 2]     = red[0] + red[2] + red[4] + red[6];
    cblk[(size_t)blockIdx.x * 2 + 1] = red[1] + red[3] + red[5] + red[7];
  }
}

// ---------------------------------------------------------------------------
// Kernel 5: final scalar. 1 block (R4-proven).
// ---------------------------------------------------------------------------
__global__ __launch_bounds__(256) void k_fin(const float* __restrict__ cblk,
                                             float* __restrict__ out) {
  const int tid = threadIdx.x;
  float sl = 0.f, sa = 0.f;
  for (int i = tid; i < 2048; i += 256) { sl += cblk[i * 2]; sa += cblk[i * 2 + 1]; }
  __shared__ float shl[256], sha[256];
  shl[tid] = sl; sha[tid] = sa;
  __syncthreads();
  for (int s = 128; s > 0; s >>= 1) {
    if (tid < s) { shl[tid] += shl[tid + s]; sha[tid] += sha[tid + s]; }
    __syncthreads();
  }
  if (tid == 0) out[0] = shl[0] / fmaxf(sha[0], 1.0f);
}

// ---------------------------------------------------------------------------
extern "C" void kernel_launch(void* const* d_in, const int* in_sizes, int n_in,
                              void* d_out, int out_size, void* d_ws, size_t ws_size,
                              hipStream_t stream) {
  const float* emb = (const float*)d_in[0];
  const int* labels = (const int*)d_in[1];
  char* ws = (char*)d_ws;
  ushort_t* abf  = (ushort_t*)(ws + A_OFF);
  float* lsum    = (float*)(ws + LSUM_OFF);
  float* S8      = (float*)(ws + S8_OFF);
  int*   cnt8    = (int*)(ws + CNT8_OFF);
  float* S       = (float*)(ws + S_OFF);
  int*   cnt     = (int*)(ws + CNT_OFF);
  float* cblk    = (float*)(ws + CBLK_OFF);
  float* out     = (float*)d_out;

  // zero radix copies (every replay)
  hipMemsetAsync(ws + S8_OFF, 0, ZERO_LEN, stream);
  hipLaunchKernelGGL(k_prep,   dim3(256),  dim3(512), 0, stream, emb, labels, abf, S8, cnt8);
  hipLaunchKernelGGL(k_reduce, dim3(3),    dim3(512), 0, stream, S8, cnt8, S, cnt);
  hipLaunchKernelGGL(k_main,   dim3(256),  dim3(512), 0, stream, abf, lsum);
  hipLaunchKernelGGL(k_row,    dim3(2048), dim3(256), 0, stream, emb, labels, S, cnt, lsum, cblk);
  hipLaunchKernelGGL(k_fin,    dim3(1),    dim3(256), 0, stream, cblk, out);
}